// Round 6
// baseline (307.198 us; speedup 1.0000x reference)
//
#include <hip/hip_runtime.h>

// GraphSAGE 2-layer + classifier on MI355X (gfx950).
// Fused design: gathers feed MFMA/classifier directly; no agg buffers.
//
//   CSR: k_bcount/k_bscan/k_bscatter (packed 4B edges) -> k_bcsr (rowptr,col)
//   t1 = bf16(x @ W1l.T), r1 = bf16(x @ W1r.T)        k_lin1d (x staged once)
//   k_agglin2: per 64-node tile: wave aggregates t1[nbrs] (4x16 lanes, 4-deep
//              unroll), h1 = relu(acc/deg + r1 + b1) -> LDS, MFMA vs [W2l;W2r]
//              -> y2, r2 (bf16)
//   k_agghead: per node wave: aggregate y2[nbrs] (8x8 lanes), h2 = relu(
//              acc/deg + r2 + b2), logit = h2 . Wc + bc

static constexpr int TPB = 256;
static constexpr int NWG = 512;   // edge-chunk workgroups

typedef __attribute__((ext_vector_type(8))) short bf16x8;
typedef __attribute__((ext_vector_type(4))) float f32x4;

__device__ __forceinline__ unsigned short f2bf(float f) {
  union { float f; unsigned u; } v; v.f = f;
  unsigned r = v.u + 0x7FFFu + ((v.u >> 16) & 1u);  // RNE
  return (unsigned short)(r >> 16);
}
__device__ __forceinline__ float bf2f(unsigned short h) {
  union { unsigned u; float f; } v; v.u = ((unsigned)h) << 16;
  return v.f;
}

// ---------------- bucket CSR build (no per-edge global atomics) -------------
__global__ void k_zero(int* __restrict__ p, int n) {
  int i = blockIdx.x * blockDim.x + threadIdx.x;
  if (i < n) p[i] = 0;
}

__global__ __launch_bounds__(TPB) void k_bcount(const int* __restrict__ dst,
                                                int* __restrict__ bcnt,
                                                int E, int NB, int EC) {
  extern __shared__ int lhist0[];  // NB ints
  int t = threadIdx.x;
  for (int b = t; b < NB; b += TPB) lhist0[b] = 0;
  __syncthreads();
  int base = blockIdx.x * EC;
  int cnt = min(EC, E - base);
  for (int i = t; i < cnt; i += TPB)
    atomicAdd(&lhist0[dst[base + i] >> 8], 1);
  __syncthreads();
  for (int b = t; b < NB; b += TPB) {
    int c = lhist0[b];
    if (c) atomicAdd(&bcnt[b], c);
  }
}

__global__ void k_bscan(const int* __restrict__ bcnt, int* __restrict__ bbase,
                        int* __restrict__ bcur, int NB) {
  __shared__ int s[512];
  int t = threadIdx.x;
  int v = (t < NB) ? bcnt[t] : 0;
  s[t] = v; __syncthreads();
  for (int off = 1; off < 512; off <<= 1) {
    int x = (t >= off) ? s[t - off] : 0;
    __syncthreads();
    s[t] += x;
    __syncthreads();
  }
  if (t < NB) {
    int e = s[t] - v;
    bbase[t] = e; bcur[t] = e;
  }
  if (t == NB - 1) bbase[NB] = s[t];
}

// stage chunk, reserve bucket runs, emit packed (dstlocal<<17 | src)
__global__ __launch_bounds__(TPB) void k_bscatter(const int* __restrict__ src,
                                                  const int* __restrict__ dst,
                                                  int* __restrict__ bcur,
                                                  int* __restrict__ ebuf,
                                                  int E, int NB, int EC) {
  extern __shared__ int smem[];
  int* pv = smem;                                   // EC packed vals
  unsigned short* kb = (unsigned short*)(pv + EC);  // EC bucket keys
  int* lhist = pv + EC + ((EC + 1) >> 1);           // NB
  int* lcur  = lhist + NB;                          // NB
  int t = threadIdx.x;
  for (int b = t; b < NB; b += TPB) lhist[b] = 0;
  int base = blockIdx.x * EC;
  int cnt = min(EC, E - base);
  __syncthreads();
  for (int i = t; i < cnt; i += TPB) {
    int sv = src[base + i], dv = dst[base + i];
    int b = dv >> 8;
    kb[i] = (unsigned short)b;
    pv[i] = ((dv & 255) << 17) | sv;
    atomicAdd(&lhist[b], 1);
  }
  __syncthreads();
  for (int b = t; b < NB; b += TPB) {
    int c = lhist[b];
    lcur[b] = c ? atomicAdd(&bcur[b], c) : 0;
  }
  __syncthreads();
  for (int i = t; i < cnt; i += TPB) {
    int b = kb[i];
    int pos = atomicAdd(&lcur[b], 1);
    ebuf[pos] = pv[i];
  }
}

// one WG per 256-node bucket: LDS degree count + scan -> rowptr, col scatter
__global__ __launch_bounds__(TPB) void k_bcsr(const int* __restrict__ ebuf,
                                              const int* __restrict__ bbase,
                                              int* __restrict__ rowptr,
                                              int* __restrict__ col,
                                              int N, int NB) {
  __shared__ int deg[256], sscan[256], lcur[256];
  int b = blockIdx.x;
  int t = threadIdx.x;
  int e0 = bbase[b], e1 = bbase[b + 1];
  int node0 = b << 8;
  deg[t] = 0;
  __syncthreads();
  for (int i = e0 + t; i < e1; i += TPB)
    atomicAdd(&deg[ebuf[i] >> 17], 1);
  __syncthreads();
  int v = deg[t];
  sscan[t] = v; __syncthreads();
  for (int off = 1; off < 256; off <<= 1) {
    int x = (t >= off) ? sscan[t - off] : 0;
    __syncthreads();
    sscan[t] += x;
    __syncthreads();
  }
  int excl = sscan[t] - v;
  if (node0 + t < N) rowptr[node0 + t] = e0 + excl;
  if (b == NB - 1 && t == 0) rowptr[N] = e1;
  lcur[t] = e0 + excl;
  __syncthreads();
  for (int i = e0 + t; i < e1; i += TPB) {
    int pv = ebuf[i];
    int pos = atomicAdd(&lcur[pv >> 17], 1);
    col[pos] = pv & 0x1FFFF;
  }
}

// ---------------- bf16 MFMA GEMM pieces ----------------
static constexpr int LD = 136;  // padded bf16 leading dim (2-way aliasing = free)

__device__ __forceinline__ void mfma_tile_128(
    const unsigned short* As, const unsigned short* Bs,
    unsigned short* __restrict__ out, int row0, int N, int w, int l) {
  int lr = l & 15, lk = l >> 4;
  f32x4 acc[4][2];
#pragma unroll
  for (int mb = 0; mb < 4; ++mb)
#pragma unroll
    for (int nb = 0; nb < 2; ++nb)
#pragma unroll
      for (int q = 0; q < 4; ++q) acc[mb][nb][q] = 0.f;
#pragma unroll
  for (int ks = 0; ks < 4; ++ks) {
    int koff = ks * 32 + lk * 8;
    bf16x8 a[4], bfr[2];
#pragma unroll
    for (int mb = 0; mb < 4; ++mb)
      a[mb] = *(const bf16x8*)&As[(mb * 16 + lr) * LD + koff];
#pragma unroll
    for (int nb = 0; nb < 2; ++nb)
      bfr[nb] = *(const bf16x8*)&Bs[(w * 32 + nb * 16 + lr) * LD + koff];
#pragma unroll
    for (int mb = 0; mb < 4; ++mb)
#pragma unroll
      for (int nb = 0; nb < 2; ++nb)
        acc[mb][nb] = __builtin_amdgcn_mfma_f32_16x16x32_bf16(a[mb], bfr[nb], acc[mb][nb], 0, 0, 0);
  }
#pragma unroll
  for (int mb = 0; mb < 4; ++mb) {
    int r = row0 + mb * 16 + lk * 4;
#pragma unroll
    for (int nb = 0; nb < 2; ++nb) {
      int c = w * 32 + nb * 16 + lr;
#pragma unroll
      for (int j = 0; j < 4; ++j)
        if (r + j < N) out[(size_t)(r + j) * 128 + c] = f2bf(acc[mb][nb][j]);
    }
  }
}

// dual-output layer-1: stage x once, run W1l then W1r
__global__ __launch_bounds__(TPB) void k_lin1d(
    const float* __restrict__ X, const float* __restrict__ W1l,
    const float* __restrict__ W1r, unsigned short* __restrict__ t1,
    unsigned short* __restrict__ r1, int N) {
  __shared__ unsigned short Bs[128 * LD];
  __shared__ unsigned short As[64 * LD];
  int t = threadIdx.x;
  int row0 = blockIdx.x * 64;
  for (int i = t; i < 64 * 32; i += TPB) {
    int r = i >> 5, k4 = i & 31;
    int gr = row0 + r;
    float4 v;
    if (gr < N) v = *(const float4*)&X[(size_t)gr * 128 + k4 * 4];
    else { v.x = v.y = v.z = v.w = 0.f; }
    ushort4 o; o.x = f2bf(v.x); o.y = f2bf(v.y); o.z = f2bf(v.z); o.w = f2bf(v.w);
    *(ushort4*)&As[r * LD + k4 * 4] = o;
  }
  for (int i = t; i < 128 * 32; i += TPB) {
    int r = i >> 5, k4 = i & 31;
    float4 v = *(const float4*)&W1l[r * 128 + k4 * 4];
    ushort4 o; o.x = f2bf(v.x); o.y = f2bf(v.y); o.z = f2bf(v.z); o.w = f2bf(v.w);
    *(ushort4*)&Bs[r * LD + k4 * 4] = o;
  }
  __syncthreads();
  int w = t >> 6, l = t & 63;
  mfma_tile_128(As, Bs, t1, row0, N, w, l);
  __syncthreads();
  for (int i = t; i < 128 * 32; i += TPB) {
    int r = i >> 5, k4 = i & 31;
    float4 v = *(const float4*)&W1r[r * 128 + k4 * 4];
    ushort4 o; o.x = f2bf(v.x); o.y = f2bf(v.y); o.z = f2bf(v.z); o.w = f2bf(v.w);
    *(ushort4*)&Bs[r * LD + k4 * 4] = o;
  }
  __syncthreads();
  mfma_tile_128(As, Bs, r1, row0, N, w, l);
}

// ---------------- fused agg1 + h1 + layer-2 GEMM ----------------
// Block = 64 nodes. Wave w aggregates nodes [row0+w*16, +16) from t1 (4 groups
// x 16 lanes x bf16x8, 4-deep unroll = 16 rows in flight), builds
// h1 = relu(acc/deg + r1 + b1) in LDS, then MFMA vs [W2l;W2r] -> y2,r2.
__global__ __launch_bounds__(TPB) void k_agglin2(
    const unsigned short* __restrict__ t1, const unsigned short* __restrict__ r1,
    const int* __restrict__ rowptr, const int* __restrict__ col,
    const float* __restrict__ b1,
    const float* __restrict__ W2l, const float* __restrict__ W2r,
    unsigned short* __restrict__ y2, unsigned short* __restrict__ r2, int N) {
  __shared__ unsigned short Bs[128 * LD];
  __shared__ unsigned short As[64 * LD];
  int t = threadIdx.x;
  for (int i = t; i < 128 * 32; i += TPB) {  // B rows 0-63: W2l, 64-127: W2r
    int r = i >> 5, k4 = i & 31;
    const float* srcp = (r < 64) ? &W2l[(size_t)r * 128 + k4 * 4]
                                 : &W2r[(size_t)(r - 64) * 128 + k4 * 4];
    float4 v = *(const float4*)srcp;
    ushort4 o; o.x = f2bf(v.x); o.y = f2bf(v.y); o.z = f2bf(v.z); o.w = f2bf(v.w);
    *(ushort4*)&Bs[r * LD + k4 * 4] = o;
  }
  int w = t >> 6, l = t & 63;
  int g = l >> 4, s = l & 15;
  int row0 = blockIdx.x * 64;
  for (int i = 0; i < 16; ++i) {
    int lrow = w * 16 + i;
    int gr = row0 + lrow;
    int rp0 = 0, rp1 = 0;
    if (gr < N) { rp0 = rowptr[gr]; rp1 = rowptr[gr + 1]; }
    float acc[8];
#pragma unroll
    for (int q = 0; q < 8; ++q) acc[q] = 0.f;
    int j = rp0 + g;
    for (; j + 12 < rp1; j += 16) {
      int c0 = col[j], c1 = col[j + 4], c2 = col[j + 8], c3 = col[j + 12];
      bf16x8 v0 = *(const bf16x8*)&t1[(size_t)c0 * 128 + s * 8];
      bf16x8 v1 = *(const bf16x8*)&t1[(size_t)c1 * 128 + s * 8];
      bf16x8 v2 = *(const bf16x8*)&t1[(size_t)c2 * 128 + s * 8];
      bf16x8 v3 = *(const bf16x8*)&t1[(size_t)c3 * 128 + s * 8];
#pragma unroll
      for (int q = 0; q < 8; ++q)
        acc[q] += (bf2f((unsigned short)v0[q]) + bf2f((unsigned short)v1[q])) +
                  (bf2f((unsigned short)v2[q]) + bf2f((unsigned short)v3[q]));
    }
    for (; j < rp1; j += 4) {
      int c0 = col[j];
      bf16x8 v0 = *(const bf16x8*)&t1[(size_t)c0 * 128 + s * 8];
#pragma unroll
      for (int q = 0; q < 8; ++q) acc[q] += bf2f((unsigned short)v0[q]);
    }
#pragma unroll
    for (int q = 0; q < 8; ++q) {
      acc[q] += __shfl_xor(acc[q], 16, 64);
      acc[q] += __shfl_xor(acc[q], 32, 64);
    }
    if (g == 0) {
      bf16x8 ov;
      if (gr < N) {
        int d = rp1 - rp0;
        float inv = 1.f / (float)(d > 1 ? d : 1);
        bf16x8 rr = *(const bf16x8*)&r1[(size_t)gr * 128 + s * 8];
        float4 bb0 = *(const float4*)&b1[s * 8];
        float4 bb1 = *(const float4*)&b1[s * 8 + 4];
        float bbv[8] = {bb0.x, bb0.y, bb0.z, bb0.w, bb1.x, bb1.y, bb1.z, bb1.w};
#pragma unroll
        for (int q = 0; q < 8; ++q) {
          float h = acc[q] * inv + bf2f((unsigned short)rr[q]) + bbv[q];
          h = h > 0.f ? h : 0.f;
          ov[q] = (short)f2bf(h);
        }
      } else {
#pragma unroll
        for (int q = 0; q < 8; ++q) ov[q] = 0;
      }
      *(bf16x8*)&As[lrow * LD + s * 8] = ov;
    }
  }
  __syncthreads();
  int lr = l & 15, lk = l >> 4;
  f32x4 acc2[4][2];
#pragma unroll
  for (int mb = 0; mb < 4; ++mb)
#pragma unroll
    for (int nb = 0; nb < 2; ++nb)
#pragma unroll
      for (int q = 0; q < 4; ++q) acc2[mb][nb][q] = 0.f;
#pragma unroll
  for (int ks = 0; ks < 4; ++ks) {
    int koff = ks * 32 + lk * 8;
    bf16x8 a[4], bfr[2];
#pragma unroll
    for (int mb = 0; mb < 4; ++mb)
      a[mb] = *(const bf16x8*)&As[(mb * 16 + lr) * LD + koff];
#pragma unroll
    for (int nb = 0; nb < 2; ++nb)
      bfr[nb] = *(const bf16x8*)&Bs[(w * 32 + nb * 16 + lr) * LD + koff];
#pragma unroll
    for (int mb = 0; mb < 4; ++mb)
#pragma unroll
      for (int nb = 0; nb < 2; ++nb)
        acc2[mb][nb] = __builtin_amdgcn_mfma_f32_16x16x32_bf16(a[mb], bfr[nb], acc2[mb][nb], 0, 0, 0);
  }
#pragma unroll
  for (int mb = 0; mb < 4; ++mb) {
    int r = row0 + mb * 16 + lk * 4;
#pragma unroll
    for (int nb = 0; nb < 2; ++nb) {
      int c = w * 32 + nb * 16 + lr;
#pragma unroll
      for (int j = 0; j < 4; ++j) {
        if (r + j < N) {
          unsigned short val = f2bf(acc2[mb][nb][j]);
          if (c < 64) y2[(size_t)(r + j) * 64 + c] = val;
          else        r2[(size_t)(r + j) * 64 + (c - 64)] = val;
        }
      }
    }
  }
}

// ---------------- fused agg2 + h2 + classifier ----------------
// Wave per node: 8 groups x 8 lanes x bf16x8, 2-deep unroll; then
// h2 = relu(acc/deg + r2 + b2), logit = h2 . Wc + bc.
__global__ void k_agghead(const unsigned short* __restrict__ y2,
                          const unsigned short* __restrict__ r2,
                          const int* __restrict__ rowptr, const int* __restrict__ col,
                          const float* __restrict__ b2, const float* __restrict__ Wc,
                          const float* __restrict__ bc, float* __restrict__ out, int n) {
  int wid = (int)(((size_t)blockIdx.x * blockDim.x + threadIdx.x) >> 6);
  int l = threadIdx.x & 63;
  if (wid >= n) return;
  int rp0 = rowptr[wid], rp1 = rowptr[wid + 1];
  int g = l >> 3, s = l & 7;
  float acc[8];
#pragma unroll
  for (int q = 0; q < 8; ++q) acc[q] = 0.f;
  int j = rp0 + g;
  for (; j + 8 < rp1; j += 16) {
    int c0 = col[j], c1 = col[j + 8];
    bf16x8 v0 = *(const bf16x8*)&y2[(size_t)c0 * 64 + s * 8];
    bf16x8 v1 = *(const bf16x8*)&y2[(size_t)c1 * 64 + s * 8];
#pragma unroll
    for (int q = 0; q < 8; ++q)
      acc[q] += bf2f((unsigned short)v0[q]) + bf2f((unsigned short)v1[q]);
  }
  if (j < rp1) {
    int c0 = col[j];
    bf16x8 v0 = *(const bf16x8*)&y2[(size_t)c0 * 64 + s * 8];
#pragma unroll
    for (int q = 0; q < 8; ++q) acc[q] += bf2f((unsigned short)v0[q]);
  }
#pragma unroll
  for (int q = 0; q < 8; ++q) {
    acc[q] += __shfl_xor(acc[q], 8, 64);
    acc[q] += __shfl_xor(acc[q], 16, 64);
    acc[q] += __shfl_xor(acc[q], 32, 64);
  }
  if (g == 0) {
    int d = rp1 - rp0;
    float inv = 1.f / (float)(d > 1 ? d : 1);
    bf16x8 rr = *(const bf16x8*)&r2[(size_t)wid * 64 + s * 8];
    float4 bb0 = *(const float4*)&b2[s * 8];
    float4 bb1 = *(const float4*)&b2[s * 8 + 4];
    float bbv[8] = {bb0.x, bb0.y, bb0.z, bb0.w, bb1.x, bb1.y, bb1.z, bb1.w};
    float4 wc0 = *(const float4*)&Wc[s * 8];
    float4 wc1 = *(const float4*)&Wc[s * 8 + 4];
    float wcv[8] = {wc0.x, wc0.y, wc0.z, wc0.w, wc1.x, wc1.y, wc1.z, wc1.w};
    float p = 0.f;
#pragma unroll
    for (int q = 0; q < 8; ++q) {
      float h = acc[q] * inv + bf2f((unsigned short)rr[q]) + bbv[q];
      h = h > 0.f ? h : 0.f;
      p += h * wcv[q];
    }
    p += __shfl_xor(p, 1, 64);
    p += __shfl_xor(p, 2, 64);
    p += __shfl_xor(p, 4, 64);
    if (s == 0) out[wid] = p + bc[0];
  }
}

extern "C" void kernel_launch(void* const* d_in, const int* in_sizes, int n_in,
                              void* d_out, int out_size, void* d_ws, size_t ws_size,
                              hipStream_t stream) {
  const float* x   = (const float*)d_in[0];
  const int*   ei  = (const int*)d_in[1];
  const float* W1l = (const float*)d_in[2];
  const float* W1r = (const float*)d_in[3];
  const float* b1  = (const float*)d_in[4];
  const float* W2l = (const float*)d_in[5];
  const float* W2r = (const float*)d_in[6];
  const float* b2  = (const float*)d_in[7];
  const float* Wc  = (const float*)d_in[8];
  const float* bc  = (const float*)d_in[9];
  float* logits = (float*)d_out;

  const int N = in_sizes[0] / 128;  // 100000
  const int E = in_sizes[1] / 2;    // 1600000
  const int NB = (N + 255) >> 8;    // 391 buckets (256 nodes each)
  const int EC = (E + NWG - 1) / NWG;  // 3125 edges per chunk WG

  char* ws = (char*)d_ws;
  size_t o = 0;
  auto alloc = [&](size_t bytes) { size_t r = o; o += (bytes + 511) & ~511ULL; return r; };
  size_t o_rp    = alloc((size_t)(N + 1) * 4);
  size_t o_bcnt  = alloc((size_t)NB * 4);
  size_t o_bbase = alloc((size_t)(NB + 1) * 4);
  size_t o_bcur  = alloc((size_t)NB * 4);
  size_t o_col   = alloc((size_t)E * 4);
  size_t o_ebuf  = alloc((size_t)E * 4);        // packed 4B edges
  size_t o_t1    = alloc((size_t)N * 128 * 2);  // bf16 gather table L1
  size_t o_r1    = alloc((size_t)N * 128 * 2);  // bf16 root transform L1
  size_t o_y2r2  = alloc((size_t)N * 128 * 2);  // y2 (N*64) | r2 (N*64) bf16
  if (o > ws_size) return;

  int* rp    = (int*)(ws + o_rp);
  int* bcnt  = (int*)(ws + o_bcnt);
  int* bbase = (int*)(ws + o_bbase);
  int* bcur  = (int*)(ws + o_bcur);
  int* col   = (int*)(ws + o_col);
  int* ebuf  = (int*)(ws + o_ebuf);
  unsigned short* t1 = (unsigned short*)(ws + o_t1);
  unsigned short* r1 = (unsigned short*)(ws + o_r1);
  unsigned short* y2 = (unsigned short*)(ws + o_y2r2);
  unsigned short* r2 = y2 + (size_t)N * 64;

  const int* esrc = ei;
  const int* edst = ei + E;

  // CSR build
  k_zero<<<(NB + TPB - 1) / TPB, TPB, 0, stream>>>(bcnt, NB);
  k_bcount<<<NWG, TPB, (size_t)NB * 4, stream>>>(edst, bcnt, E, NB, EC);
  k_bscan<<<1, 512, 0, stream>>>(bcnt, bbase, bcur, NB);
  size_t scat_lds = (size_t)(EC + ((EC + 1) >> 1) + 2 * NB) * 4;  // ~22KB
  k_bscatter<<<NWG, TPB, scat_lds, stream>>>(esrc, edst, bcur, ebuf, E, NB, EC);
  k_bcsr<<<NB, TPB, 0, stream>>>(ebuf, bbase, rp, col, N, NB);

  int gtiles = (N + 63) / 64;                               // 1563
  int nodeblocks = (int)(((size_t)N * 64 + TPB - 1) / TPB); // 25000

  k_lin1d<<<gtiles, TPB, 0, stream>>>(x, W1l, W1r, t1, r1, N);
  k_agglin2<<<gtiles, TPB, 0, stream>>>(t1, r1, rp, col, b1, W2l, W2r, y2, r2, N);
  k_agghead<<<nodeblocks, TPB, 0, stream>>>(y2, r2, rp, col, b2, Wc, bc, logits, N);
}

// Round 7
// 233.806 us; speedup vs baseline: 1.3139x; 1.3139x over previous
//
#include <hip/hip_runtime.h>

// GraphSAGE 2-layer + classifier on MI355X (gfx950).
// Wave-per-node gathers (MLP-bound: need fat grids), MFMA GEMMs, bucket CSR.
//
//   CSR: k_bcount/k_bscan/k_bscatter (packed 4B edges) -> k_bcsr (rowptr,col)
//   t1 = bf16(x @ W1l.T), r1 = bf16(x @ W1r.T)        k_lin1d (x staged once)
//   h1 = bf16(relu(gather-sum(t1)/deg + r1 + b1))     k_aggh1 (wave per node)
//   y2,r2 = bf16(h1 @ [W2l;W2r].T)                    k_lin2  (pure GEMM)
//   logit = relu(gather-sum(y2)/deg + r2 + b2).Wc+bc  k_agghead (wave per node)

static constexpr int TPB = 256;
static constexpr int NWG = 512;   // edge-chunk workgroups

typedef __attribute__((ext_vector_type(8))) short bf16x8;
typedef __attribute__((ext_vector_type(4))) float f32x4;

__device__ __forceinline__ unsigned short f2bf(float f) {
  union { float f; unsigned u; } v; v.f = f;
  unsigned r = v.u + 0x7FFFu + ((v.u >> 16) & 1u);  // RNE
  return (unsigned short)(r >> 16);
}
__device__ __forceinline__ float bf2f(unsigned short h) {
  union { unsigned u; float f; } v; v.u = ((unsigned)h) << 16;
  return v.f;
}

// ---------------- bucket CSR build (no per-edge global atomics) -------------
__global__ void k_zero(int* __restrict__ p, int n) {
  int i = blockIdx.x * blockDim.x + threadIdx.x;
  if (i < n) p[i] = 0;
}

__global__ __launch_bounds__(TPB) void k_bcount(const int* __restrict__ dst,
                                                int* __restrict__ bcnt,
                                                int E, int NB, int EC) {
  extern __shared__ int lhist0[];  // NB ints
  int t = threadIdx.x;
  for (int b = t; b < NB; b += TPB) lhist0[b] = 0;
  __syncthreads();
  int base = blockIdx.x * EC;
  int cnt = min(EC, E - base);
  for (int i = t; i < cnt; i += TPB)
    atomicAdd(&lhist0[dst[base + i] >> 8], 1);
  __syncthreads();
  for (int b = t; b < NB; b += TPB) {
    int c = lhist0[b];
    if (c) atomicAdd(&bcnt[b], c);
  }
}

__global__ void k_bscan(const int* __restrict__ bcnt, int* __restrict__ bbase,
                        int* __restrict__ bcur, int NB) {
  __shared__ int s[512];
  int t = threadIdx.x;
  int v = (t < NB) ? bcnt[t] : 0;
  s[t] = v; __syncthreads();
  for (int off = 1; off < 512; off <<= 1) {
    int x = (t >= off) ? s[t - off] : 0;
    __syncthreads();
    s[t] += x;
    __syncthreads();
  }
  if (t < NB) {
    int e = s[t] - v;
    bbase[t] = e; bcur[t] = e;
  }
  if (t == NB - 1) bbase[NB] = s[t];
}

// stage chunk, reserve bucket runs, emit packed (dstlocal<<17 | src)
__global__ __launch_bounds__(TPB) void k_bscatter(const int* __restrict__ src,
                                                  const int* __restrict__ dst,
                                                  int* __restrict__ bcur,
                                                  int* __restrict__ ebuf,
                                                  int E, int NB, int EC) {
  extern __shared__ int smem[];
  int* pv = smem;                                   // EC packed vals
  unsigned short* kb = (unsigned short*)(pv + EC);  // EC bucket keys
  int* lhist = pv + EC + ((EC + 1) >> 1);           // NB
  int* lcur  = lhist + NB;                          // NB
  int t = threadIdx.x;
  for (int b = t; b < NB; b += TPB) lhist[b] = 0;
  int base = blockIdx.x * EC;
  int cnt = min(EC, E - base);
  __syncthreads();
  for (int i = t; i < cnt; i += TPB) {
    int sv = src[base + i], dv = dst[base + i];
    int b = dv >> 8;
    kb[i] = (unsigned short)b;
    pv[i] = ((dv & 255) << 17) | sv;
    atomicAdd(&lhist[b], 1);
  }
  __syncthreads();
  for (int b = t; b < NB; b += TPB) {
    int c = lhist[b];
    lcur[b] = c ? atomicAdd(&bcur[b], c) : 0;
  }
  __syncthreads();
  for (int i = t; i < cnt; i += TPB) {
    int b = kb[i];
    int pos = atomicAdd(&lcur[b], 1);
    ebuf[pos] = pv[i];
  }
}

// one WG per 256-node bucket: LDS degree count + scan -> rowptr, col scatter
__global__ __launch_bounds__(TPB) void k_bcsr(const int* __restrict__ ebuf,
                                              const int* __restrict__ bbase,
                                              int* __restrict__ rowptr,
                                              int* __restrict__ col,
                                              int N, int NB) {
  __shared__ int deg[256], sscan[256], lcur[256];
  int b = blockIdx.x;
  int t = threadIdx.x;
  int e0 = bbase[b], e1 = bbase[b + 1];
  int node0 = b << 8;
  deg[t] = 0;
  __syncthreads();
  for (int i = e0 + t; i < e1; i += TPB)
    atomicAdd(&deg[ebuf[i] >> 17], 1);
  __syncthreads();
  int v = deg[t];
  sscan[t] = v; __syncthreads();
  for (int off = 1; off < 256; off <<= 1) {
    int x = (t >= off) ? sscan[t - off] : 0;
    __syncthreads();
    sscan[t] += x;
    __syncthreads();
  }
  int excl = sscan[t] - v;
  if (node0 + t < N) rowptr[node0 + t] = e0 + excl;
  if (b == NB - 1 && t == 0) rowptr[N] = e1;
  lcur[t] = e0 + excl;
  __syncthreads();
  for (int i = e0 + t; i < e1; i += TPB) {
    int pv = ebuf[i];
    int pos = atomicAdd(&lcur[pv >> 17], 1);
    col[pos] = pv & 0x1FFFF;
  }
}

// ---------------- bf16 MFMA GEMM pieces ----------------
static constexpr int LD = 136;  // padded bf16 leading dim (2-way aliasing = free)

__device__ __forceinline__ void mfma_tile_128(
    const unsigned short* As, const unsigned short* Bs,
    unsigned short* __restrict__ out, int row0, int N, int w, int l) {
  int lr = l & 15, lk = l >> 4;
  f32x4 acc[4][2];
#pragma unroll
  for (int mb = 0; mb < 4; ++mb)
#pragma unroll
    for (int nb = 0; nb < 2; ++nb)
#pragma unroll
      for (int q = 0; q < 4; ++q) acc[mb][nb][q] = 0.f;
#pragma unroll
  for (int ks = 0; ks < 4; ++ks) {
    int koff = ks * 32 + lk * 8;
    bf16x8 a[4], bfr[2];
#pragma unroll
    for (int mb = 0; mb < 4; ++mb)
      a[mb] = *(const bf16x8*)&As[(mb * 16 + lr) * LD + koff];
#pragma unroll
    for (int nb = 0; nb < 2; ++nb)
      bfr[nb] = *(const bf16x8*)&Bs[(w * 32 + nb * 16 + lr) * LD + koff];
#pragma unroll
    for (int mb = 0; mb < 4; ++mb)
#pragma unroll
      for (int nb = 0; nb < 2; ++nb)
        acc[mb][nb] = __builtin_amdgcn_mfma_f32_16x16x32_bf16(a[mb], bfr[nb], acc[mb][nb], 0, 0, 0);
  }
#pragma unroll
  for (int mb = 0; mb < 4; ++mb) {
    int r = row0 + mb * 16 + lk * 4;
#pragma unroll
    for (int nb = 0; nb < 2; ++nb) {
      int c = w * 32 + nb * 16 + lr;
#pragma unroll
      for (int j = 0; j < 4; ++j)
        if (r + j < N) out[(size_t)(r + j) * 128 + c] = f2bf(acc[mb][nb][j]);
    }
  }
}

// dual-output layer-1: stage x once, run W1l then W1r
__global__ __launch_bounds__(TPB) void k_lin1d(
    const float* __restrict__ X, const float* __restrict__ W1l,
    const float* __restrict__ W1r, unsigned short* __restrict__ t1,
    unsigned short* __restrict__ r1, int N) {
  __shared__ unsigned short Bs[128 * LD];
  __shared__ unsigned short As[64 * LD];
  int t = threadIdx.x;
  int row0 = blockIdx.x * 64;
  for (int i = t; i < 64 * 32; i += TPB) {
    int r = i >> 5, k4 = i & 31;
    int gr = row0 + r;
    float4 v;
    if (gr < N) v = *(const float4*)&X[(size_t)gr * 128 + k4 * 4];
    else { v.x = v.y = v.z = v.w = 0.f; }
    ushort4 o; o.x = f2bf(v.x); o.y = f2bf(v.y); o.z = f2bf(v.z); o.w = f2bf(v.w);
    *(ushort4*)&As[r * LD + k4 * 4] = o;
  }
  for (int i = t; i < 128 * 32; i += TPB) {
    int r = i >> 5, k4 = i & 31;
    float4 v = *(const float4*)&W1l[r * 128 + k4 * 4];
    ushort4 o; o.x = f2bf(v.x); o.y = f2bf(v.y); o.z = f2bf(v.z); o.w = f2bf(v.w);
    *(ushort4*)&Bs[r * LD + k4 * 4] = o;
  }
  __syncthreads();
  int w = t >> 6, l = t & 63;
  mfma_tile_128(As, Bs, t1, row0, N, w, l);
  __syncthreads();
  for (int i = t; i < 128 * 32; i += TPB) {
    int r = i >> 5, k4 = i & 31;
    float4 v = *(const float4*)&W1r[r * 128 + k4 * 4];
    ushort4 o; o.x = f2bf(v.x); o.y = f2bf(v.y); o.z = f2bf(v.z); o.w = f2bf(v.w);
    *(ushort4*)&Bs[r * LD + k4 * 4] = o;
  }
  __syncthreads();
  mfma_tile_128(As, Bs, r1, row0, N, w, l);
}

// ---------------- gather + h1 (wave per node) ----------------
// 4 groups x 16 lanes x bf16x8; 2-deep unroll -> 8 rows in flight per wave.
// h1 = relu(acc/deg + r1 + b1) folded in (r1 read + VALU hide under latency).
__global__ void k_aggh1(const unsigned short* __restrict__ t1,
                        const unsigned short* __restrict__ r1,
                        const int* __restrict__ rowptr, const int* __restrict__ col,
                        const float* __restrict__ b1,
                        unsigned short* __restrict__ h1, int n) {
  int wid = (int)(((size_t)blockIdx.x * blockDim.x + threadIdx.x) >> 6);
  int l = threadIdx.x & 63;
  if (wid >= n) return;
  int rp0 = rowptr[wid], rp1 = rowptr[wid + 1];
  int g = l >> 4, s = l & 15;
  float acc[8];
#pragma unroll
  for (int q = 0; q < 8; ++q) acc[q] = 0.f;
  int j = rp0 + g;
  for (; j + 4 < rp1; j += 8) {
    int c0 = col[j], c1 = col[j + 4];
    bf16x8 v0 = *(const bf16x8*)&t1[(size_t)c0 * 128 + s * 8];
    bf16x8 v1 = *(const bf16x8*)&t1[(size_t)c1 * 128 + s * 8];
#pragma unroll
    for (int q = 0; q < 8; ++q)
      acc[q] += bf2f((unsigned short)v0[q]) + bf2f((unsigned short)v1[q]);
  }
  if (j < rp1) {
    int c0 = col[j];
    bf16x8 v0 = *(const bf16x8*)&t1[(size_t)c0 * 128 + s * 8];
#pragma unroll
    for (int q = 0; q < 8; ++q) acc[q] += bf2f((unsigned short)v0[q]);
  }
#pragma unroll
  for (int q = 0; q < 8; ++q) {
    acc[q] += __shfl_xor(acc[q], 16, 64);
    acc[q] += __shfl_xor(acc[q], 32, 64);
  }
  if (g == 0) {
    int d = rp1 - rp0;
    float inv = 1.f / (float)(d > 1 ? d : 1);
    bf16x8 rr = *(const bf16x8*)&r1[(size_t)wid * 128 + s * 8];
    float4 bb0 = *(const float4*)&b1[s * 8];
    float4 bb1 = *(const float4*)&b1[s * 8 + 4];
    float bbv[8] = {bb0.x, bb0.y, bb0.z, bb0.w, bb1.x, bb1.y, bb1.z, bb1.w};
    bf16x8 o;
#pragma unroll
    for (int q = 0; q < 8; ++q) {
      float h = acc[q] * inv + bf2f((unsigned short)rr[q]) + bbv[q];
      h = h > 0.f ? h : 0.f;
      o[q] = (short)f2bf(h);
    }
    *(bf16x8*)&h1[(size_t)wid * 128 + s * 8] = o;
  }
}

// layer-2 pure GEMM: y2,r2 = bf16(h1 @ [W2l;W2r].T)
__global__ __launch_bounds__(TPB) void k_lin2(
    const unsigned short* __restrict__ h1,
    const float* __restrict__ W2l, const float* __restrict__ W2r,
    unsigned short* __restrict__ y2, unsigned short* __restrict__ r2, int N) {
  __shared__ unsigned short Bs[128 * LD];
  __shared__ unsigned short As[64 * LD];
  int t = threadIdx.x;
  for (int i = t; i < 128 * 32; i += TPB) {  // B rows 0-63: W2l, 64-127: W2r
    int r = i >> 5, k4 = i & 31;
    const float* srcp = (r < 64) ? &W2l[(size_t)r * 128 + k4 * 4]
                                 : &W2r[(size_t)(r - 64) * 128 + k4 * 4];
    float4 v = *(const float4*)srcp;
    ushort4 o; o.x = f2bf(v.x); o.y = f2bf(v.y); o.z = f2bf(v.z); o.w = f2bf(v.w);
    *(ushort4*)&Bs[r * LD + k4 * 4] = o;
  }
  int row0 = blockIdx.x * 64;
  for (int i = t * 8; i < 64 * 128; i += TPB * 8) {
    int r = i >> 7, k8 = i & 127;
    int gr = row0 + r;
    bf16x8 v;
    if (gr < N) v = *(const bf16x8*)&h1[(size_t)gr * 128 + k8];
    else { for (int q = 0; q < 8; ++q) v[q] = 0; }
    *(bf16x8*)&As[r * LD + k8] = v;
  }
  __syncthreads();
  int w = t >> 6, l = t & 63;
  int lr = l & 15, lk = l >> 4;
  f32x4 acc[4][2];
#pragma unroll
  for (int mb = 0; mb < 4; ++mb)
#pragma unroll
    for (int nb = 0; nb < 2; ++nb)
#pragma unroll
      for (int q = 0; q < 4; ++q) acc[mb][nb][q] = 0.f;
#pragma unroll
  for (int ks = 0; ks < 4; ++ks) {
    int koff = ks * 32 + lk * 8;
    bf16x8 a[4], bfr[2];
#pragma unroll
    for (int mb = 0; mb < 4; ++mb)
      a[mb] = *(const bf16x8*)&As[(mb * 16 + lr) * LD + koff];
#pragma unroll
    for (int nb = 0; nb < 2; ++nb)
      bfr[nb] = *(const bf16x8*)&Bs[(w * 32 + nb * 16 + lr) * LD + koff];
#pragma unroll
    for (int mb = 0; mb < 4; ++mb)
#pragma unroll
      for (int nb = 0; nb < 2; ++nb)
        acc[mb][nb] = __builtin_amdgcn_mfma_f32_16x16x32_bf16(a[mb], bfr[nb], acc[mb][nb], 0, 0, 0);
  }
#pragma unroll
  for (int mb = 0; mb < 4; ++mb) {
    int r = row0 + mb * 16 + lk * 4;
#pragma unroll
    for (int nb = 0; nb < 2; ++nb) {
      int c = w * 32 + nb * 16 + lr;
#pragma unroll
      for (int j = 0; j < 4; ++j) {
        if (r + j < N) {
          unsigned short val = f2bf(acc[mb][nb][j]);
          if (c < 64) y2[(size_t)(r + j) * 64 + c] = val;
          else        r2[(size_t)(r + j) * 64 + (c - 64)] = val;
        }
      }
    }
  }
}

// ---------------- fused agg2 + h2 + classifier (wave per node) --------------
__global__ void k_agghead(const unsigned short* __restrict__ y2,
                          const unsigned short* __restrict__ r2,
                          const int* __restrict__ rowptr, const int* __restrict__ col,
                          const float* __restrict__ b2, const float* __restrict__ Wc,
                          const float* __restrict__ bc, float* __restrict__ out, int n) {
  int wid = (int)(((size_t)blockIdx.x * blockDim.x + threadIdx.x) >> 6);
  int l = threadIdx.x & 63;
  if (wid >= n) return;
  int rp0 = rowptr[wid], rp1 = rowptr[wid + 1];
  int g = l >> 3, s = l & 7;
  float acc[8];
#pragma unroll
  for (int q = 0; q < 8; ++q) acc[q] = 0.f;
  int j = rp0 + g;
  for (; j + 8 < rp1; j += 16) {
    int c0 = col[j], c1 = col[j + 8];
    bf16x8 v0 = *(const bf16x8*)&y2[(size_t)c0 * 64 + s * 8];
    bf16x8 v1 = *(const bf16x8*)&y2[(size_t)c1 * 64 + s * 8];
#pragma unroll
    for (int q = 0; q < 8; ++q)
      acc[q] += bf2f((unsigned short)v0[q]) + bf2f((unsigned short)v1[q]);
  }
  if (j < rp1) {
    int c0 = col[j];
    bf16x8 v0 = *(const bf16x8*)&y2[(size_t)c0 * 64 + s * 8];
#pragma unroll
    for (int q = 0; q < 8; ++q) acc[q] += bf2f((unsigned short)v0[q]);
  }
#pragma unroll
  for (int q = 0; q < 8; ++q) {
    acc[q] += __shfl_xor(acc[q], 8, 64);
    acc[q] += __shfl_xor(acc[q], 16, 64);
    acc[q] += __shfl_xor(acc[q], 32, 64);
  }
  if (g == 0) {
    int d = rp1 - rp0;
    float inv = 1.f / (float)(d > 1 ? d : 1);
    bf16x8 rr = *(const bf16x8*)&r2[(size_t)wid * 64 + s * 8];
    float4 bb0 = *(const float4*)&b2[s * 8];
    float4 bb1 = *(const float4*)&b2[s * 8 + 4];
    float bbv[8] = {bb0.x, bb0.y, bb0.z, bb0.w, bb1.x, bb1.y, bb1.z, bb1.w};
    float4 wc0 = *(const float4*)&Wc[s * 8];
    float4 wc1 = *(const float4*)&Wc[s * 8 + 4];
    float wcv[8] = {wc0.x, wc0.y, wc0.z, wc0.w, wc1.x, wc1.y, wc1.z, wc1.w};
    float p = 0.f;
#pragma unroll
    for (int q = 0; q < 8; ++q) {
      float h = acc[q] * inv + bf2f((unsigned short)rr[q]) + bbv[q];
      h = h > 0.f ? h : 0.f;
      p += h * wcv[q];
    }
    p += __shfl_xor(p, 1, 64);
    p += __shfl_xor(p, 2, 64);
    p += __shfl_xor(p, 4, 64);
    if (s == 0) out[wid] = p + bc[0];
  }
}

extern "C" void kernel_launch(void* const* d_in, const int* in_sizes, int n_in,
                              void* d_out, int out_size, void* d_ws, size_t ws_size,
                              hipStream_t stream) {
  const float* x   = (const float*)d_in[0];
  const int*   ei  = (const int*)d_in[1];
  const float* W1l = (const float*)d_in[2];
  const float* W1r = (const float*)d_in[3];
  const float* b1  = (const float*)d_in[4];
  const float* W2l = (const float*)d_in[5];
  const float* W2r = (const float*)d_in[6];
  const float* b2  = (const float*)d_in[7];
  const float* Wc  = (const float*)d_in[8];
  const float* bc  = (const float*)d_in[9];
  float* logits = (float*)d_out;

  const int N = in_sizes[0] / 128;  // 100000
  const int E = in_sizes[1] / 2;    // 1600000
  const int NB = (N + 255) >> 8;    // 391 buckets (256 nodes each)
  const int EC = (E + NWG - 1) / NWG;  // 3125 edges per chunk WG

  char* ws = (char*)d_ws;
  size_t o = 0;
  auto alloc = [&](size_t bytes) { size_t r = o; o += (bytes + 511) & ~511ULL; return r; };
  size_t o_rp    = alloc((size_t)(N + 1) * 4);
  size_t o_bcnt  = alloc((size_t)NB * 4);
  size_t o_bbase = alloc((size_t)(NB + 1) * 4);
  size_t o_bcur  = alloc((size_t)NB * 4);
  size_t o_col   = alloc((size_t)E * 4);
  size_t o_ebuf  = alloc((size_t)E * 4);        // packed 4B edges
  size_t o_t1    = alloc((size_t)N * 128 * 2);  // bf16 gather table L1
  size_t o_r1    = alloc((size_t)N * 128 * 2);  // bf16 root transform; reused h1
  size_t o_h1    = alloc((size_t)N * 128 * 2);  // bf16 h1
  size_t o_y2r2  = alloc((size_t)N * 128 * 2);  // y2 (N*64) | r2 (N*64) bf16
  if (o > ws_size) return;

  int* rp    = (int*)(ws + o_rp);
  int* bcnt  = (int*)(ws + o_bcnt);
  int* bbase = (int*)(ws + o_bbase);
  int* bcur  = (int*)(ws + o_bcur);
  int* col   = (int*)(ws + o_col);
  int* ebuf  = (int*)(ws + o_ebuf);
  unsigned short* t1 = (unsigned short*)(ws + o_t1);
  unsigned short* r1 = (unsigned short*)(ws + o_r1);
  unsigned short* h1 = (unsigned short*)(ws + o_h1);
  unsigned short* y2 = (unsigned short*)(ws + o_y2r2);
  unsigned short* r2 = y2 + (size_t)N * 64;

  const int* esrc = ei;
  const int* edst = ei + E;

  // CSR build
  k_zero<<<(NB + TPB - 1) / TPB, TPB, 0, stream>>>(bcnt, NB);
  k_bcount<<<NWG, TPB, (size_t)NB * 4, stream>>>(edst, bcnt, E, NB, EC);
  k_bscan<<<1, 512, 0, stream>>>(bcnt, bbase, bcur, NB);
  size_t scat_lds = (size_t)(EC + ((EC + 1) >> 1) + 2 * NB) * 4;  // ~22KB
  k_bscatter<<<NWG, TPB, scat_lds, stream>>>(esrc, edst, bcur, ebuf, E, NB, EC);
  k_bcsr<<<NB, TPB, 0, stream>>>(ebuf, bbase, rp, col, N, NB);

  int gtiles = (N + 63) / 64;                               // 1563
  int nodeblocks = (int)(((size_t)N * 64 + TPB - 1) / TPB); // 25000

  k_lin1d<<<gtiles, TPB, 0, stream>>>(x, W1l, W1r, t1, r1, N);
  k_aggh1<<<nodeblocks, TPB, 0, stream>>>(t1, r1, rp, col, b1, h1, N);
  k_lin2<<<gtiles, TPB, 0, stream>>>(h1, W2l, W2r, y2, r2, N);
  k_agghead<<<nodeblocks, TPB, 0, stream>>>(y2, r2, rp, col, b2, Wc, bc, logits, N);
}